// Round 1
// baseline (139.832 us; speedup 1.0000x reference)
//
#include <hip/hip_runtime.h>

// MLPPredictor: score[e] = concat(nfeats[src[e]], nfeats[dst[e]], efeats[e]) @ W^T + b
// E = 625000, D = 128, OUT = 2. Memory-bound gather + tiny GEMV.
//
// Layout: 32 lanes per edge. Lane sl handles floats [4*sl, 4*sl+4) of each
// 128-float segment (one float4 load per segment -> full 512 B row per group,
// coalesced). W fragments hoisted to registers, shfl_xor tree reduction,
// lane 0 writes float2.

static constexpr int D = 128;
static constexpr int THREADS = 256;
static constexpr int GROUPS_PER_BLOCK = THREADS / 32;  // 8 edges in flight per block

__global__ __launch_bounds__(THREADS) void mlp_pred_kernel(
    const float* __restrict__ nfeats,   // [N, 128]
    const float* __restrict__ efeats,   // [E, 128]
    const int*   __restrict__ src,      // [E]
    const int*   __restrict__ dst,      // [E]
    const float* __restrict__ W,        // [2, 384]
    const float* __restrict__ bias,     // [2]
    float*       __restrict__ out,      // [E, 2]
    int E)
{
    const int sl   = threadIdx.x & 31;         // sub-lane within the 32-lane group
    const int gib  = threadIdx.x >> 5;         // group index within block
    const int g0   = blockIdx.x * GROUPS_PER_BLOCK + gib;
    const int ngrp = gridDim.x * GROUPS_PER_BLOCK;

    // Hoist W fragments for this lane (same for every edge).
    const float4 w0s = *reinterpret_cast<const float4*>(W +   0 + 4 * sl);
    const float4 w0d = *reinterpret_cast<const float4*>(W + 128 + 4 * sl);
    const float4 w0e = *reinterpret_cast<const float4*>(W + 256 + 4 * sl);
    const float4 w1s = *reinterpret_cast<const float4*>(W + 384 +   0 + 4 * sl);
    const float4 w1d = *reinterpret_cast<const float4*>(W + 384 + 128 + 4 * sl);
    const float4 w1e = *reinterpret_cast<const float4*>(W + 384 + 256 + 4 * sl);
    const float b0 = bias[0];
    const float b1 = bias[1];

    for (int e = g0; e < E; e += ngrp) {
        const int si = src[e];
        const int di = dst[e];

        const float4 hs = *reinterpret_cast<const float4*>(nfeats + (size_t)si * D + 4 * sl);
        const float4 hd = *reinterpret_cast<const float4*>(nfeats + (size_t)di * D + 4 * sl);
        const float4 he = *reinterpret_cast<const float4*>(efeats + (size_t)e  * D + 4 * sl);

        float a0 = hs.x * w0s.x + hs.y * w0s.y + hs.z * w0s.z + hs.w * w0s.w;
        a0 += hd.x * w0d.x + hd.y * w0d.y + hd.z * w0d.z + hd.w * w0d.w;
        a0 += he.x * w0e.x + he.y * w0e.y + he.z * w0e.z + he.w * w0e.w;

        float a1 = hs.x * w1s.x + hs.y * w1s.y + hs.z * w1s.z + hs.w * w1s.w;
        a1 += hd.x * w1d.x + hd.y * w1d.y + hd.z * w1d.z + hd.w * w1d.w;
        a1 += he.x * w1e.x + he.y * w1e.y + he.z * w1e.z + he.w * w1e.w;

        // 32-lane tree reduction (xor masks < 32 never cross the group boundary)
        #pragma unroll
        for (int off = 16; off; off >>= 1) {
            a0 += __shfl_xor(a0, off);
            a1 += __shfl_xor(a1, off);
        }

        if (sl == 0) {
            *reinterpret_cast<float2*>(out + 2 * (size_t)e) = make_float2(a0 + b0, a1 + b1);
        }
    }
}

extern "C" void kernel_launch(void* const* d_in, const int* in_sizes, int n_in,
                              void* d_out, int out_size, void* d_ws, size_t ws_size,
                              hipStream_t stream) {
    const float* nfeats = (const float*)d_in[0];
    const float* efeats = (const float*)d_in[1];
    const int*   src    = (const int*)d_in[2];
    const int*   dst    = (const int*)d_in[3];
    const float* W      = (const float*)d_in[4];
    const float* bias   = (const float*)d_in[5];
    float*       out    = (float*)d_out;

    const int E = in_sizes[2];  // 625000 edges

    const int groups_needed = E;  // one 32-lane group per edge per pass
    int blocks = (groups_needed + GROUPS_PER_BLOCK - 1) / GROUPS_PER_BLOCK;
    if (blocks > 2048) blocks = 2048;  // grid-stride; 8 blocks/CU * 4 waves = full occupancy

    mlp_pred_kernel<<<blocks, THREADS, 0, stream>>>(nfeats, efeats, src, dst, W, bias, out, E);
}

// Round 3
// 106.391 us; speedup vs baseline: 1.3143x; 1.3143x over previous
//
#include <hip/hip_runtime.h>

// MLPPredictor: score[e] = concat(nfeats[src[e]], nfeats[dst[e]], efeats[e]) @ W^T + b
// E = 625000, N = 100000, D = 128, OUT = 2.
//
// Two-kernel split of the affine map:
//   p[n] = (nfeats[n]@W[0,0:128], nfeats[n]@W[1,0:128],
//           nfeats[n]@W[0,128:256], nfeats[n]@W[1,128:256])   -> float4 table, 1.6 MB
//   score[e] = (p[src].x + p[dst].z + efeats[e]@W[0,256:384] + b0,
//               p[src].y + p[dst].w + efeats[e]@W[1,256:384] + b1)
// Turns 2x512B random gathers/edge into 2x16B L2-resident loads.

static constexpr int D = 128;
static constexpr int THREADS = 256;
static constexpr int GPB = THREADS / 32;  // 32-lane groups per block

// clang ext vectors for nontemporal builtins (HIP_vector_type is rejected)
typedef float f32x4 __attribute__((ext_vector_type(4)));
typedef float f32x2 __attribute__((ext_vector_type(2)));

// ---------- kernel 1: per-node partial dot products ----------
__global__ __launch_bounds__(THREADS) void node_partial_kernel(
    const float* __restrict__ nfeats,   // [N, 128]
    const float* __restrict__ W,        // [2, 384]
    float4*      __restrict__ p,        // [N] (s0, s1, d0, d1)
    int N)
{
    const int sl   = threadIdx.x & 31;
    const int gib  = threadIdx.x >> 5;
    const int g0   = blockIdx.x * GPB + gib;
    const int ngrp = gridDim.x * GPB;

    const float4 w0s = *reinterpret_cast<const float4*>(W +   0 + 4 * sl);
    const float4 w1s = *reinterpret_cast<const float4*>(W + 384 + 4 * sl);
    const float4 w0d = *reinterpret_cast<const float4*>(W + 128 + 4 * sl);
    const float4 w1d = *reinterpret_cast<const float4*>(W + 384 + 128 + 4 * sl);

    for (int n = g0; n < N; n += ngrp) {
        const float4 h = *reinterpret_cast<const float4*>(nfeats + (size_t)n * D + 4 * sl);

        float s0 = h.x * w0s.x + h.y * w0s.y + h.z * w0s.z + h.w * w0s.w;
        float s1 = h.x * w1s.x + h.y * w1s.y + h.z * w1s.z + h.w * w1s.w;
        float d0 = h.x * w0d.x + h.y * w0d.y + h.z * w0d.z + h.w * w0d.w;
        float d1 = h.x * w1d.x + h.y * w1d.y + h.z * w1d.z + h.w * w1d.w;

        #pragma unroll
        for (int off = 16; off; off >>= 1) {
            s0 += __shfl_xor(s0, off);
            s1 += __shfl_xor(s1, off);
            d0 += __shfl_xor(d0, off);
            d1 += __shfl_xor(d1, off);
        }
        if (sl == 0) p[n] = make_float4(s0, s1, d0, d1);
    }
}

// ---------- kernel 2: streamed edge kernel ----------
__global__ __launch_bounds__(THREADS) void edge_kernel(
    const float*  __restrict__ efeats,  // [E, 128]
    const int*    __restrict__ src,     // [E]
    const int*    __restrict__ dst,     // [E]
    const float*  __restrict__ W,       // [2, 384]
    const float*  __restrict__ bias,    // [2]
    const float4* __restrict__ p,       // [N]
    float*        __restrict__ out,     // [E, 2]
    int E)
{
    const int sl   = threadIdx.x & 31;
    const int gib  = threadIdx.x >> 5;
    const int g0   = blockIdx.x * GPB + gib;
    const int ngrp = gridDim.x * GPB;

    const float4 w0e = *reinterpret_cast<const float4*>(W + 256 + 4 * sl);
    const float4 w1e = *reinterpret_cast<const float4*>(W + 384 + 256 + 4 * sl);
    const float b0 = bias[0];
    const float b1 = bias[1];

    for (int e = g0; e < E; e += ngrp) {
        const int si = src[e];
        const int di = dst[e];
        // same address across the 32-lane group -> single broadcast transaction;
        // table is 1.6 MB, L2-resident.
        const float4 ps = p[si];
        const float4 pd = p[di];

        // streaming read, nontemporal so it doesn't evict the p table from L2
        const f32x4 he = __builtin_nontemporal_load(
            reinterpret_cast<const f32x4*>(efeats + (size_t)e * D + 4 * sl));

        float a0 = he.x * w0e.x + he.y * w0e.y + he.z * w0e.z + he.w * w0e.w;
        float a1 = he.x * w1e.x + he.y * w1e.y + he.z * w1e.z + he.w * w1e.w;

        #pragma unroll
        for (int off = 16; off; off >>= 1) {
            a0 += __shfl_xor(a0, off);
            a1 += __shfl_xor(a1, off);
        }

        if (sl == 0) {
            f32x2 r;
            r.x = a0 + ps.x + pd.z + b0;
            r.y = a1 + ps.y + pd.w + b1;
            __builtin_nontemporal_store(r, reinterpret_cast<f32x2*>(out + 2 * (size_t)e));
        }
    }
}

// ---------- fallback: round-1 single-kernel (if ws too small) ----------
__global__ __launch_bounds__(THREADS) void mlp_pred_fused_kernel(
    const float* __restrict__ nfeats, const float* __restrict__ efeats,
    const int* __restrict__ src, const int* __restrict__ dst,
    const float* __restrict__ W, const float* __restrict__ bias,
    float* __restrict__ out, int E)
{
    const int sl = threadIdx.x & 31;
    const int gib = threadIdx.x >> 5;
    const int g0 = blockIdx.x * GPB + gib;
    const int ngrp = gridDim.x * GPB;

    const float4 w0s = *reinterpret_cast<const float4*>(W +   0 + 4 * sl);
    const float4 w0d = *reinterpret_cast<const float4*>(W + 128 + 4 * sl);
    const float4 w0e = *reinterpret_cast<const float4*>(W + 256 + 4 * sl);
    const float4 w1s = *reinterpret_cast<const float4*>(W + 384 +   0 + 4 * sl);
    const float4 w1d = *reinterpret_cast<const float4*>(W + 384 + 128 + 4 * sl);
    const float4 w1e = *reinterpret_cast<const float4*>(W + 384 + 256 + 4 * sl);
    const float b0 = bias[0];
    const float b1 = bias[1];

    for (int e = g0; e < E; e += ngrp) {
        const int si = src[e];
        const int di = dst[e];
        const float4 hs = *reinterpret_cast<const float4*>(nfeats + (size_t)si * D + 4 * sl);
        const float4 hd = *reinterpret_cast<const float4*>(nfeats + (size_t)di * D + 4 * sl);
        const float4 he = *reinterpret_cast<const float4*>(efeats + (size_t)e  * D + 4 * sl);

        float a0 = hs.x * w0s.x + hs.y * w0s.y + hs.z * w0s.z + hs.w * w0s.w;
        a0 += hd.x * w0d.x + hd.y * w0d.y + hd.z * w0d.z + hd.w * w0d.w;
        a0 += he.x * w0e.x + he.y * w0e.y + he.z * w0e.z + he.w * w0e.w;
        float a1 = hs.x * w1s.x + hs.y * w1s.y + hs.z * w1s.z + hs.w * w1s.w;
        a1 += hd.x * w1d.x + hd.y * w1d.y + hd.z * w1d.z + hd.w * w1d.w;
        a1 += he.x * w1e.x + he.y * w1e.y + he.z * w1e.z + he.w * w1e.w;

        #pragma unroll
        for (int off = 16; off; off >>= 1) {
            a0 += __shfl_xor(a0, off);
            a1 += __shfl_xor(a1, off);
        }
        if (sl == 0)
            *reinterpret_cast<float2*>(out + 2 * (size_t)e) = make_float2(a0 + b0, a1 + b1);
    }
}

extern "C" void kernel_launch(void* const* d_in, const int* in_sizes, int n_in,
                              void* d_out, int out_size, void* d_ws, size_t ws_size,
                              hipStream_t stream) {
    const float* nfeats = (const float*)d_in[0];
    const float* efeats = (const float*)d_in[1];
    const int*   src    = (const int*)d_in[2];
    const int*   dst    = (const int*)d_in[3];
    const float* W      = (const float*)d_in[4];
    const float* bias   = (const float*)d_in[5];
    float*       out    = (float*)d_out;

    const int E = in_sizes[2];
    const int N = in_sizes[0] / D;

    const size_t p_bytes = (size_t)N * sizeof(float4);

    if (ws_size >= p_bytes) {
        float4* p = (float4*)d_ws;

        int blocks1 = (N + GPB - 1) / GPB;
        if (blocks1 > 4096) blocks1 = 4096;
        node_partial_kernel<<<blocks1, THREADS, 0, stream>>>(nfeats, W, p, N);

        int blocks2 = (E + GPB - 1) / GPB;
        if (blocks2 > 2048) blocks2 = 2048;
        edge_kernel<<<blocks2, THREADS, 0, stream>>>(efeats, src, dst, W, bias, p, out, E);
    } else {
        int blocks = (E + GPB - 1) / GPB;
        if (blocks > 2048) blocks = 2048;
        mlp_pred_fused_kernel<<<blocks, THREADS, 0, stream>>>(nfeats, efeats, src, dst, W, bias, out, E);
    }
}

// Round 4
// 89.411 us; speedup vs baseline: 1.5639x; 1.1899x over previous
//
#include <hip/hip_runtime.h>

// MLPPredictor: score[e] = concat(nfeats[src[e]], nfeats[dst[e]], efeats[e]) @ W^T + b
// E = 625000, N = 100000, D = 128, OUT = 2.
//
// Two-kernel affine split + 4-edge batching per 32-lane group:
//   p[n] = (n@W0s, n@W1s, n@W0d, n@W1d)  -> float4 table (1.6 MB, L2-resident)
//   score[e] = efeats[e]@We + p[src].xy + p[dst].zw + b
// Batching x4 gives each wave 4 independent load+reduce chains (MLP/ILP),
// int4 index loads, and 32 B contiguous output stores.

static constexpr int D = 128;
static constexpr int THREADS = 256;
static constexpr int GPB = THREADS / 32;  // 32-lane groups per block

typedef float f32x4 __attribute__((ext_vector_type(4)));
typedef float f32x2 __attribute__((ext_vector_type(2)));

// ---------- kernel 1: per-node partial dot products (2 nodes per group) ----------
__global__ __launch_bounds__(THREADS) void node_partial_kernel(
    const float* __restrict__ nfeats,   // [N, 128]
    const float* __restrict__ W,        // [2, 384]
    float4*      __restrict__ p,        // [N] (s0, s1, d0, d1)
    int N)
{
    const int sl   = threadIdx.x & 31;
    const int gib  = threadIdx.x >> 5;
    const int g0   = blockIdx.x * GPB + gib;
    const int ngrp = gridDim.x * GPB;

    const float4 w0s = *reinterpret_cast<const float4*>(W +   0 + 4 * sl);
    const float4 w1s = *reinterpret_cast<const float4*>(W + 384 + 4 * sl);
    const float4 w0d = *reinterpret_cast<const float4*>(W + 128 + 4 * sl);
    const float4 w1d = *reinterpret_cast<const float4*>(W + 384 + 128 + 4 * sl);

    // N = 100000 is even; process 2 nodes per group-iteration.
    for (int n = g0 * 2; n + 1 < N; n += ngrp * 2) {
        float acc[2][4];
        #pragma unroll
        for (int j = 0; j < 2; ++j) {
            const float4 h = *reinterpret_cast<const float4*>(nfeats + (size_t)(n + j) * D + 4 * sl);
            acc[j][0] = h.x * w0s.x + h.y * w0s.y + h.z * w0s.z + h.w * w0s.w;
            acc[j][1] = h.x * w1s.x + h.y * w1s.y + h.z * w1s.z + h.w * w1s.w;
            acc[j][2] = h.x * w0d.x + h.y * w0d.y + h.z * w0d.z + h.w * w0d.w;
            acc[j][3] = h.x * w1d.x + h.y * w1d.y + h.z * w1d.z + h.w * w1d.w;
        }
        #pragma unroll
        for (int off = 16; off; off >>= 1) {
            #pragma unroll
            for (int j = 0; j < 2; ++j) {
                acc[j][0] += __shfl_xor(acc[j][0], off);
                acc[j][1] += __shfl_xor(acc[j][1], off);
                acc[j][2] += __shfl_xor(acc[j][2], off);
                acc[j][3] += __shfl_xor(acc[j][3], off);
            }
        }
        if (sl == 0) {
            p[n]     = make_float4(acc[0][0], acc[0][1], acc[0][2], acc[0][3]);
            p[n + 1] = make_float4(acc[1][0], acc[1][1], acc[1][2], acc[1][3]);
        }
    }
}

// ---------- kernel 2: streamed edge kernel (4 edges per group) ----------
__global__ __launch_bounds__(THREADS) void edge_kernel(
    const float*  __restrict__ efeats,  // [E, 128]
    const int*    __restrict__ src,     // [E]
    const int*    __restrict__ dst,     // [E]
    const float*  __restrict__ W,       // [2, 384]
    const float*  __restrict__ bias,    // [2]
    const float4* __restrict__ p,       // [N]
    float*        __restrict__ out,     // [E, 2]
    int E)
{
    const int sl   = threadIdx.x & 31;
    const int gib  = threadIdx.x >> 5;
    const int g0   = blockIdx.x * GPB + gib;
    const int ngrp = gridDim.x * GPB;

    const float4 w0e = *reinterpret_cast<const float4*>(W + 256 + 4 * sl);
    const float4 w1e = *reinterpret_cast<const float4*>(W + 384 + 256 + 4 * sl);
    const float b0 = bias[0];
    const float b1 = bias[1];

    // E = 625000 is a multiple of 4: no tail path needed for e = 4*g.
    for (int e = g0 * 4; e + 3 < E; e += ngrp * 4) {
        const int4 s4 = *reinterpret_cast<const int4*>(src + e);
        const int4 d4 = *reinterpret_cast<const int4*>(dst + e);

        // 8 independent 16 B L2-resident gathers (uniform per group)
        const float4 ps0 = p[s4.x], ps1 = p[s4.y], ps2 = p[s4.z], ps3 = p[s4.w];
        const float4 pd0 = p[d4.x], pd1 = p[d4.y], pd2 = p[d4.z], pd3 = p[d4.w];

        // 4 independent streaming row loads (wave covers 4 KB contiguous)
        f32x4 he[4];
        #pragma unroll
        for (int j = 0; j < 4; ++j)
            he[j] = __builtin_nontemporal_load(
                reinterpret_cast<const f32x4*>(efeats + (size_t)(e + j) * D + 4 * sl));

        float a[4][2];
        #pragma unroll
        for (int j = 0; j < 4; ++j) {
            a[j][0] = he[j].x * w0e.x + he[j].y * w0e.y + he[j].z * w0e.z + he[j].w * w0e.w;
            a[j][1] = he[j].x * w1e.x + he[j].y * w1e.y + he[j].z * w1e.z + he[j].w * w1e.w;
        }

        // 8 interleaved (independent) reduction chains
        #pragma unroll
        for (int off = 16; off; off >>= 1) {
            #pragma unroll
            for (int j = 0; j < 4; ++j) {
                a[j][0] += __shfl_xor(a[j][0], off);
                a[j][1] += __shfl_xor(a[j][1], off);
            }
        }

        if (sl == 0) {
            f32x4 r01, r23;
            r01.x = a[0][0] + ps0.x + pd0.z + b0;
            r01.y = a[0][1] + ps0.y + pd0.w + b1;
            r01.z = a[1][0] + ps1.x + pd1.z + b0;
            r01.w = a[1][1] + ps1.y + pd1.w + b1;
            r23.x = a[2][0] + ps2.x + pd2.z + b0;
            r23.y = a[2][1] + ps2.y + pd2.w + b1;
            r23.z = a[3][0] + ps3.x + pd3.z + b0;
            r23.w = a[3][1] + ps3.y + pd3.w + b1;
            // out + 2e is 32 B aligned (e % 4 == 0)
            __builtin_nontemporal_store(r01, reinterpret_cast<f32x4*>(out + 2 * (size_t)e));
            __builtin_nontemporal_store(r23, reinterpret_cast<f32x4*>(out + 2 * (size_t)e + 4));
        }
    }
}

// ---------- fallback: single-kernel (if ws too small) ----------
__global__ __launch_bounds__(THREADS) void mlp_pred_fused_kernel(
    const float* __restrict__ nfeats, const float* __restrict__ efeats,
    const int* __restrict__ src, const int* __restrict__ dst,
    const float* __restrict__ W, const float* __restrict__ bias,
    float* __restrict__ out, int E)
{
    const int sl = threadIdx.x & 31;
    const int gib = threadIdx.x >> 5;
    const int g0 = blockIdx.x * GPB + gib;
    const int ngrp = gridDim.x * GPB;

    const float4 w0s = *reinterpret_cast<const float4*>(W +   0 + 4 * sl);
    const float4 w0d = *reinterpret_cast<const float4*>(W + 128 + 4 * sl);
    const float4 w0e = *reinterpret_cast<const float4*>(W + 256 + 4 * sl);
    const float4 w1s = *reinterpret_cast<const float4*>(W + 384 +   0 + 4 * sl);
    const float4 w1d = *reinterpret_cast<const float4*>(W + 384 + 128 + 4 * sl);
    const float4 w1e = *reinterpret_cast<const float4*>(W + 384 + 256 + 4 * sl);
    const float b0 = bias[0];
    const float b1 = bias[1];

    for (int e = g0; e < E; e += ngrp) {
        const int si = src[e];
        const int di = dst[e];
        const float4 hs = *reinterpret_cast<const float4*>(nfeats + (size_t)si * D + 4 * sl);
        const float4 hd = *reinterpret_cast<const float4*>(nfeats + (size_t)di * D + 4 * sl);
        const float4 he = *reinterpret_cast<const float4*>(efeats + (size_t)e  * D + 4 * sl);

        float a0 = hs.x * w0s.x + hs.y * w0s.y + hs.z * w0s.z + hs.w * w0s.w;
        a0 += hd.x * w0d.x + hd.y * w0d.y + hd.z * w0d.z + hd.w * w0d.w;
        a0 += he.x * w0e.x + he.y * w0e.y + he.z * w0e.z + he.w * w0e.w;
        float a1 = hs.x * w1s.x + hs.y * w1s.y + hs.z * w1s.z + hs.w * w1s.w;
        a1 += hd.x * w1d.x + hd.y * w1d.y + hd.z * w1d.z + hd.w * w1d.w;
        a1 += he.x * w1e.x + he.y * w1e.y + he.z * w1e.z + he.w * w1e.w;

        #pragma unroll
        for (int off = 16; off; off >>= 1) {
            a0 += __shfl_xor(a0, off);
            a1 += __shfl_xor(a1, off);
        }
        if (sl == 0)
            *reinterpret_cast<float2*>(out + 2 * (size_t)e) = make_float2(a0 + b0, a1 + b1);
    }
}

extern "C" void kernel_launch(void* const* d_in, const int* in_sizes, int n_in,
                              void* d_out, int out_size, void* d_ws, size_t ws_size,
                              hipStream_t stream) {
    const float* nfeats = (const float*)d_in[0];
    const float* efeats = (const float*)d_in[1];
    const int*   src    = (const int*)d_in[2];
    const int*   dst    = (const int*)d_in[3];
    const float* W      = (const float*)d_in[4];
    const float* bias   = (const float*)d_in[5];
    float*       out    = (float*)d_out;

    const int E = in_sizes[2];
    const int N = in_sizes[0] / D;

    const size_t p_bytes = (size_t)N * sizeof(float4);

    if (ws_size >= p_bytes && (E & 3) == 0 && (N & 1) == 0) {
        float4* p = (float4*)d_ws;

        int groups1 = (N + 1) / 2;
        int blocks1 = (groups1 + GPB - 1) / GPB;
        if (blocks1 > 2048) blocks1 = 2048;
        node_partial_kernel<<<blocks1, THREADS, 0, stream>>>(nfeats, W, p, N);

        int groups2 = E / 4;
        int blocks2 = (groups2 + GPB - 1) / GPB;
        if (blocks2 > 2048) blocks2 = 2048;
        edge_kernel<<<blocks2, THREADS, 0, stream>>>(efeats, src, dst, W, bias, p, out, E);
    } else {
        int blocks = (E + GPB - 1) / GPB;
        if (blocks > 2048) blocks = 2048;
        mlp_pred_fused_kernel<<<blocks, THREADS, 0, stream>>>(nfeats, efeats, src, dst, W, bias, out, E);
    }
}

// Round 5
// 84.868 us; speedup vs baseline: 1.6476x; 1.0535x over previous
//
#include <hip/hip_runtime.h>

// MLPPredictor: score[e] = concat(nfeats[src[e]], nfeats[dst[e]], efeats[e]) @ W^T + b
// E = 625000, N = 100000, D = 128, OUT = 2.
//
// Two-kernel affine split:
//   p[n] = (n@W0s, n@W1s, n@W0d, n@W1d)  -> float4 table (1.6 MB, L2-resident)
//   score[e] = efeats[e]@We + p[src].xy + p[dst].zw + b
//
// Edge kernel: 8 edges per 32-lane group per iteration, fold-reduction:
// 16 chains (8 edges x 2 outputs) reduced with 16 shuffles instead of 80.
// After the fold, even lane sl holds the sum for chain c = sl>>1
// (edge j = c>>1, output o = c&1); 16 writer lanes store 4 B each ->
// one coalesced 64 B store per group. Writers gather their own idx + p parts.

static constexpr int D = 128;
static constexpr int THREADS = 256;
static constexpr int GPB = THREADS / 32;  // 32-lane groups per block

typedef float f32x4 __attribute__((ext_vector_type(4)));

// ---------- kernel 1: per-node partial dot products (2 nodes/group, fold) ----------
__global__ __launch_bounds__(THREADS) void node_partial_kernel(
    const float* __restrict__ nfeats,   // [N, 128]
    const float* __restrict__ W,        // [2, 384]
    float*       __restrict__ pf,       // [N*4] (s0, s1, d0, d1) per node
    int N)
{
    const int sl   = threadIdx.x & 31;
    const int gib  = threadIdx.x >> 5;
    const int g0   = blockIdx.x * GPB + gib;
    const int ngrp = gridDim.x * GPB;

    const float4 w0s = *reinterpret_cast<const float4*>(W +   0 + 4 * sl);
    const float4 w1s = *reinterpret_cast<const float4*>(W + 384 + 4 * sl);
    const float4 w0d = *reinterpret_cast<const float4*>(W + 128 + 4 * sl);
    const float4 w1d = *reinterpret_cast<const float4*>(W + 384 + 128 + 4 * sl);

    for (int n = g0 * 2; n + 1 < N; n += ngrp * 2) {
        // chains c = j*4 + k, j = node (0/1), k = component (s0,s1,d0,d1)
        float v[8];
        #pragma unroll
        for (int j = 0; j < 2; ++j) {
            const f32x4 h = __builtin_nontemporal_load(
                reinterpret_cast<const f32x4*>(nfeats + (size_t)(n + j) * D + 4 * sl));
            v[j*4+0] = h.x * w0s.x + h.y * w0s.y + h.z * w0s.z + h.w * w0s.w;
            v[j*4+1] = h.x * w1s.x + h.y * w1s.y + h.z * w1s.z + h.w * w1s.w;
            v[j*4+2] = h.x * w0d.x + h.y * w0d.y + h.z * w0d.z + h.w * w0d.w;
            v[j*4+3] = h.x * w1d.x + h.y * w1d.y + h.z * w1d.z + h.w * w1d.w;
        }
        // fold 8 -> 4 -> 2 -> 1  (masks 16, 8, 4), then butterfly masks 2,1
        float a4[4];
        #pragma unroll
        for (int c = 0; c < 4; ++c) {
            float send = (sl & 16) ? v[c] : v[c+4];
            float keep = (sl & 16) ? v[c+4] : v[c];
            a4[c] = keep + __shfl_xor(send, 16);
        }
        float a2[2];
        #pragma unroll
        for (int c = 0; c < 2; ++c) {
            float send = (sl & 8) ? a4[c] : a4[c+2];
            float keep = (sl & 8) ? a4[c+2] : a4[c];
            a2[c] = keep + __shfl_xor(send, 8);
        }
        float y;
        {
            float send = (sl & 4) ? a2[0] : a2[1];
            float keep = (sl & 4) ? a2[1] : a2[0];
            y = keep + __shfl_xor(send, 4);
        }
        y += __shfl_xor(y, 2);
        y += __shfl_xor(y, 1);
        // writer lane sl (sl&3==0) holds chain c = (sl>>2)&7
        if ((sl & 3) == 0) {
            pf[4 * (size_t)n + (sl >> 2)] = y;   // 8 consecutive floats = 32 B
        }
    }
}

// ---------- kernel 2: streamed edge kernel (8 edges/group, fold) ----------
__global__ __launch_bounds__(THREADS) void edge_kernel(
    const float*  __restrict__ efeats,  // [E, 128]
    const int*    __restrict__ src,     // [E]
    const int*    __restrict__ dst,     // [E]
    const float*  __restrict__ W,       // [2, 384]
    const float*  __restrict__ bias,    // [2]
    const float*  __restrict__ pf,      // [N*4]
    float*        __restrict__ out,     // [E, 2]
    int E)
{
    const int sl   = threadIdx.x & 31;
    const int gib  = threadIdx.x >> 5;
    const int g0   = blockIdx.x * GPB + gib;
    const int ngrp = gridDim.x * GPB;

    const float4 w0e = *reinterpret_cast<const float4*>(W + 256 + 4 * sl);
    const float4 w1e = *reinterpret_cast<const float4*>(W + 384 + 256 + 4 * sl);

    const bool wr   = (sl & 1) == 0;
    const int  myj  = sl >> 2;          // writer's edge within the 8-batch
    const int  myo  = (sl >> 1) & 1;    // writer's output index
    const float myb = myo ? bias[1] : bias[0];

    // E % 8 == 0 for this problem; loop condition keeps it safe anyway.
    for (int e = g0 * 8; e + 7 < E; e += ngrp * 8) {
        // writers fetch their own indices early (latency hidden under FMA+fold)
        int sidx = 0, didx = 0;
        if (wr) {
            sidx = src[e + myj];
            didx = dst[e + myj];
        }

        // chains c = j*2 + o
        float v[16];
        #pragma unroll
        for (int j = 0; j < 8; ++j) {
            const f32x4 he = __builtin_nontemporal_load(
                reinterpret_cast<const f32x4*>(efeats + (size_t)(e + j) * D + 4 * sl));
            v[2*j]   = he.x * w0e.x + he.y * w0e.y + he.z * w0e.z + he.w * w0e.w;
            v[2*j+1] = he.x * w1e.x + he.y * w1e.y + he.z * w1e.z + he.w * w1e.w;
        }

        // writers gather p parts (depends on idx; still overlapped with fold)
        float ps = 0.f, pd = 0.f;
        if (wr) {
            ps = pf[(size_t)sidx * 4 + myo];
            pd = pf[(size_t)didx * 4 + 2 + myo];
        }

        // fold 16 -> 8 -> 4 -> 2 -> 1 (masks 16,8,4,2), then butterfly mask 1
        float a8[8];
        #pragma unroll
        for (int c = 0; c < 8; ++c) {
            float send = (sl & 16) ? v[c] : v[c+8];
            float keep = (sl & 16) ? v[c+8] : v[c];
            a8[c] = keep + __shfl_xor(send, 16);
        }
        float a4[4];
        #pragma unroll
        for (int c = 0; c < 4; ++c) {
            float send = (sl & 8) ? a8[c] : a8[c+4];
            float keep = (sl & 8) ? a8[c+4] : a8[c];
            a4[c] = keep + __shfl_xor(send, 8);
        }
        float a2[2];
        #pragma unroll
        for (int c = 0; c < 2; ++c) {
            float send = (sl & 4) ? a2[0] * 0.f + a4[c] : a4[c+2];  // see note
            float keep = (sl & 4) ? a4[c+2] : a4[c];
            a2[c] = keep + __shfl_xor(send, 4);
        }
        float y;
        {
            float send = (sl & 2) ? a2[0] : a2[1];
            float keep = (sl & 2) ? a2[1] : a2[0];
            y = keep + __shfl_xor(send, 2);
        }
        y += __shfl_xor(y, 1);

        // even lane sl holds chain c = sl>>1; out[2e + c] -> 64 B coalesced/group
        if (wr) {
            out[2 * (size_t)e + (sl >> 1)] = y + ps + pd + myb;
        }
    }
}

// ---------- fallback: single-kernel (if ws too small) ----------
__global__ __launch_bounds__(THREADS) void mlp_pred_fused_kernel(
    const float* __restrict__ nfeats, const float* __restrict__ efeats,
    const int* __restrict__ src, const int* __restrict__ dst,
    const float* __restrict__ W, const float* __restrict__ bias,
    float* __restrict__ out, int E)
{
    const int sl = threadIdx.x & 31;
    const int gib = threadIdx.x >> 5;
    const int g0 = blockIdx.x * GPB + gib;
    const int ngrp = gridDim.x * GPB;

    const float4 w0s = *reinterpret_cast<const float4*>(W +   0 + 4 * sl);
    const float4 w0d = *reinterpret_cast<const float4*>(W + 128 + 4 * sl);
    const float4 w0e = *reinterpret_cast<const float4*>(W + 256 + 4 * sl);
    const float4 w1s = *reinterpret_cast<const float4*>(W + 384 +   0 + 4 * sl);
    const float4 w1d = *reinterpret_cast<const float4*>(W + 384 + 128 + 4 * sl);
    const float4 w1e = *reinterpret_cast<const float4*>(W + 384 + 256 + 4 * sl);
    const float b0 = bias[0];
    const float b1 = bias[1];

    for (int e = g0; e < E; e += ngrp) {
        const int si = src[e];
        const int di = dst[e];
        const float4 hs = *reinterpret_cast<const float4*>(nfeats + (size_t)si * D + 4 * sl);
        const float4 hd = *reinterpret_cast<const float4*>(nfeats + (size_t)di * D + 4 * sl);
        const float4 he = *reinterpret_cast<const float4*>(efeats + (size_t)e  * D + 4 * sl);

        float a0 = hs.x * w0s.x + hs.y * w0s.y + hs.z * w0s.z + hs.w * w0s.w;
        a0 += hd.x * w0d.x + hd.y * w0d.y + hd.z * w0d.z + hd.w * w0d.w;
        a0 += he.x * w0e.x + he.y * w0e.y + he.z * w0e.z + he.w * w0e.w;
        float a1 = hs.x * w1s.x + hs.y * w1s.y + hs.z * w1s.z + hs.w * w1s.w;
        a1 += hd.x * w1d.x + hd.y * w1d.y + hd.z * w1d.z + hd.w * w1d.w;
        a1 += he.x * w1e.x + he.y * w1e.y + he.z * w1e.z + he.w * w1e.w;

        #pragma unroll
        for (int off = 16; off; off >>= 1) {
            a0 += __shfl_xor(a0, off);
            a1 += __shfl_xor(a1, off);
        }
        if (sl == 0)
            *reinterpret_cast<float2*>(out + 2 * (size_t)e) = make_float2(a0 + b0, a1 + b1);
    }
}

extern "C" void kernel_launch(void* const* d_in, const int* in_sizes, int n_in,
                              void* d_out, int out_size, void* d_ws, size_t ws_size,
                              hipStream_t stream) {
    const float* nfeats = (const float*)d_in[0];
    const float* efeats = (const float*)d_in[1];
    const int*   src    = (const int*)d_in[2];
    const int*   dst    = (const int*)d_in[3];
    const float* W      = (const float*)d_in[4];
    const float* bias   = (const float*)d_in[5];
    float*       out    = (float*)d_out;

    const int E = in_sizes[2];
    const int N = in_sizes[0] / D;

    const size_t p_bytes = (size_t)N * 4 * sizeof(float);

    if (ws_size >= p_bytes && (E & 7) == 0 && (N & 1) == 0) {
        float* pf = (float*)d_ws;

        int groups1 = N / 2;
        int blocks1 = (groups1 + GPB - 1) / GPB;
        if (blocks1 > 2048) blocks1 = 2048;
        node_partial_kernel<<<blocks1, THREADS, 0, stream>>>(nfeats, W, pf, N);

        int groups2 = E / 8;
        int blocks2 = (groups2 + GPB - 1) / GPB;
        if (blocks2 > 2048) blocks2 = 2048;
        edge_kernel<<<blocks2, THREADS, 0, stream>>>(efeats, src, dst, W, bias, pf, out, E);
    } else {
        int blocks = (E + GPB - 1) / GPB;
        if (blocks > 2048) blocks = 2048;
        mlp_pred_fused_kernel<<<blocks, THREADS, 0, stream>>>(nfeats, efeats, src, dst, W, bias, out, E);
    }
}